// Round 3
// baseline (1382.531 us; speedup 1.0000x reference)
//
#include <hip/hip_runtime.h>

typedef __attribute__((ext_vector_type(8))) short short8;
typedef __attribute__((ext_vector_type(4))) float f32x4;

__device__ __forceinline__ float bf2f(unsigned short u) {
  unsigned int x = ((unsigned int)u) << 16;
  float f;
  __builtin_memcpy(&f, &x, 4);
  return f;
}
__device__ __forceinline__ unsigned short f2bf(float f) {
  unsigned int x;
  __builtin_memcpy(&x, &f, 4);
  unsigned int r = (x + 0x7FFFu + ((x >> 16) & 1u)) >> 16;
  return (unsigned short)r;
}
// load 8 consecutive fp32, round to bf16
__device__ __forceinline__ short8 ld8_f32(const float* p) {
  f32x4 x = *(const f32x4*)p;
  f32x4 y = *(const f32x4*)(p + 4);
  short8 r;
  r[0] = (short)f2bf(x[0]); r[1] = (short)f2bf(x[1]);
  r[2] = (short)f2bf(x[2]); r[3] = (short)f2bf(x[3]);
  r[4] = (short)f2bf(y[0]); r[5] = (short)f2bf(y[1]);
  r[6] = (short)f2bf(y[2]); r[7] = (short)f2bf(y[3]);
  return r;
}

// ---------------------------------------------------------------------------
// Transpose + downcast: in fp32 (R x C) -> out bf16 (C x R)
// ---------------------------------------------------------------------------
__global__ void transpose_f2b(const float* __restrict__ in,
                              unsigned short* __restrict__ out, int R, int Ccols) {
  __shared__ unsigned short tile[32][33];
  const int c0 = blockIdx.x * 32;
  const int r0 = blockIdx.y * 32;
  const int tx = threadIdx.x, ty = threadIdx.y;
#pragma unroll
  for (int i = 0; i < 32; i += 8)
    tile[ty + i][tx] = f2bf(in[(size_t)(r0 + ty + i) * Ccols + (c0 + tx)]);
  __syncthreads();
#pragma unroll
  for (int i = 0; i < 32; i += 8)
    out[(size_t)(c0 + ty + i) * R + (r0 + tx)] = tile[tx][ty + i];
}

// ---------------------------------------------------------------------------
// GEMM: C (MxN) = A (MxK) @ BT^T, BT bf16 (NxK). fp32 accum.
// AF32: A is fp32 (convert during staging) else bf16. CF32: C fp32 else bf16.
// 128x128 tile, BK=32, 4 waves, reg-round-trip staging, padded LDS.
// ---------------------------------------------------------------------------
#define LDK 40

template <int AF32, int CF32>
__global__ __launch_bounds__(256, 2) void gemm_bt(
    const void* __restrict__ Ap, const unsigned short* __restrict__ BT,
    void* __restrict__ Cp, int M, int N, int K) {
  alignas(16) __shared__ unsigned short lA[128 * LDK];
  alignas(16) __shared__ unsigned short lB[128 * LDK];
  const int tid = threadIdx.x;
  const int lane = tid & 63;
  const int wid = tid >> 6;
  const int wr = wid >> 1, wc = wid & 1;
  const int bm = blockIdx.x * 128;
  const int bn = blockIdx.y * 128;

  const int ar = tid >> 2;        // row within 64-row half
  const int ac = (tid & 3) << 3;  // col 0,8,16,24

  const unsigned short* bS0 = BT + (size_t)(bn + ar) * K + ac;
  const unsigned short* bS1 = BT + (size_t)(bn + 64 + ar) * K + ac;

  const int fr = lane & 15;         // fragment m/n index
  const int fk = (lane >> 4) << 3;  // k offset (8 contiguous)

  f32x4 acc[4][4] = {};

  for (int kt = 0; kt < K; kt += 32) {
    short8 a0, a1;
    if constexpr (AF32) {
      const float* A = (const float*)Ap;
      a0 = ld8_f32(A + (size_t)(bm + ar) * K + ac + kt);
      a1 = ld8_f32(A + (size_t)(bm + 64 + ar) * K + ac + kt);
    } else {
      const unsigned short* A = (const unsigned short*)Ap;
      a0 = *(const short8*)(A + (size_t)(bm + ar) * K + ac + kt);
      a1 = *(const short8*)(A + (size_t)(bm + 64 + ar) * K + ac + kt);
    }
    short8 b0 = *(const short8*)(bS0 + kt);
    short8 b1 = *(const short8*)(bS1 + kt);
    __syncthreads();  // prev iteration's fragment reads must finish
    *(short8*)(lA + (ar)*LDK + ac) = a0;
    *(short8*)(lA + (64 + ar) * LDK + ac) = a1;
    *(short8*)(lB + (ar)*LDK + ac) = b0;
    *(short8*)(lB + (64 + ar) * LDK + ac) = b1;
    __syncthreads();
    short8 af[4], bfr[4];
#pragma unroll
    for (int i = 0; i < 4; i++) {
      af[i] = *(const short8*)(lA + (wr * 64 + i * 16 + fr) * LDK + fk);
      bfr[i] = *(const short8*)(lB + (wc * 64 + i * 16 + fr) * LDK + fk);
    }
#pragma unroll
    for (int i = 0; i < 4; i++)
#pragma unroll
      for (int j = 0; j < 4; j++)
        acc[i][j] = __builtin_amdgcn_mfma_f32_16x16x32_bf16(af[i], bfr[j], acc[i][j], 0, 0, 0);
  }

  // C/D layout: col = lane&15, row = (lane>>4)*4 + r
  const int er = (lane >> 4) << 2;
#pragma unroll
  for (int i = 0; i < 4; i++) {
#pragma unroll
    for (int j = 0; j < 4; j++) {
      int row = bm + wr * 64 + i * 16 + er;
      int col = bn + wc * 64 + j * 16 + fr;
#pragma unroll
      for (int r = 0; r < 4; r++) {
        if constexpr (CF32)
          ((float*)Cp)[(size_t)(row + r) * N + col] = acc[i][j][r];
        else
          ((unsigned short*)Cp)[(size_t)(row + r) * N + col] = f2bf(acc[i][j][r]);
      }
    }
  }
}

// ---------------------------------------------------------------------------
// RoPE in-place on bf16 buf (4096 tokens x nh*128). cos/sin fp32 (2048 x 128).
// 8 threads per (token, head); thread handles 8 pairs (d, d+64).
// cos[d+64]==cos[d], sin[d+64]==sin[d] (emb = concat(freqs,freqs)).
// ---------------------------------------------------------------------------
__global__ void rope_kernel(unsigned short* __restrict__ buf,
                            const float* __restrict__ cosb,
                            const float* __restrict__ sinb,
                            int nh_shift, int total) {
  int gid = blockIdx.x * 256 + threadIdx.x;
  if (gid >= total) return;
  int dblk = gid & 7;
  int u = gid >> 3;
  int head = u & ((1 << nh_shift) - 1);
  int token = u >> nh_shift;
  int s = token & 2047;
  int d0 = dblk << 3;
  unsigned short* p0 = buf + ((size_t)token << (7 + nh_shift)) + (head << 7) + d0;
  unsigned short* p1 = p0 + 64;
  const float* cp = cosb + s * 128 + d0;
  const float* sp = sinb + s * 128 + d0;
  short8 a = *(const short8*)p0;
  short8 bq = *(const short8*)p1;
  f32x4 c0 = *(const f32x4*)cp, c1 = *(const f32x4*)(cp + 4);
  f32x4 s0 = *(const f32x4*)sp, s1 = *(const f32x4*)(sp + 4);
  short8 o0, o1;
#pragma unroll
  for (int j = 0; j < 8; j++) {
    float x0 = bf2f((unsigned short)a[j]);
    float x1 = bf2f((unsigned short)bq[j]);
    float c = (j < 4) ? c0[j & 3] : c1[j & 3];
    float sn = (j < 4) ? s0[j & 3] : s1[j & 3];
    o0[j] = (short)f2bf(x0 * c - x1 * sn);
    o1[j] = (short)f2bf(x1 * c + x0 * sn);
  }
  *(short8*)p0 = o0;
  *(short8*)p1 = o1;
}

// ---------------------------------------------------------------------------
// Flash attention, causal, GQA (grp=4). All-bf16 buffers. Plain padded LDS.
// 256 thr / 4 waves; QBLK=64 (wave w owns q rows w*16..+16), KVBLK=64.
// Online softmax in registers + shfl reduce over 16 lanes.
// ---------------------------------------------------------------------------
#define LKD 136  // lK row stride (shorts): rows kv (64) x cols d (128)
#define LVD 72   // lV row stride: rows d (128) x cols kv (64)  (V transposed)
#define LPD 72   // lP row stride: rows q (64) x cols kv (64)
#define ATT_SCALE 0.08838834764831845f
#define NEGBIG -30000.0f

__global__ __launch_bounds__(256, 2) void flash_attn(
    const unsigned short* __restrict__ Q, const unsigned short* __restrict__ K,
    const unsigned short* __restrict__ V, unsigned short* __restrict__ O) {
  alignas(16) __shared__ unsigned short lK[64 * LKD];
  alignas(16) __shared__ unsigned short lV[128 * LVD];
  alignas(16) __shared__ unsigned short lP[64 * LPD];

  const int tid = threadIdx.x;
  const int lane = tid & 63;
  const int w = tid >> 6;
  const int b = blockIdx.z;
  const int h = blockIdx.y;
  const int q0 = blockIdx.x * 64;
  const int kvh = h >> 2;

  const int fr = lane & 15;
  const int fk8 = (lane >> 4) << 3;
  const int erow = (lane >> 4) << 2;

  // Q fragments in registers: row = q0 + w*16 + fr, k = ks*32 + fk8 + [0..8)
  short8 qf[4];
  {
    const unsigned short* qb =
        Q + (size_t)(b * 2048 + q0 + w * 16 + fr) * 4096 + h * 128 + fk8;
#pragma unroll
    for (int ks = 0; ks < 4; ks++) qf[ks] = *(const short8*)(qb + ks * 32);
  }

  const int srow = tid >> 4;        // 0..15
  const int sc8 = (tid & 15) << 3;  // 0..120 (d chunk)
  const unsigned short* Kbp = K + (size_t)(b * 2048) * 1024 + kvh * 128;
  const unsigned short* Vbp = V + (size_t)(b * 2048) * 1024 + kvh * 128;

  f32x4 oacc[8] = {};
  float m[4] = {NEGBIG, NEGBIG, NEGBIG, NEGBIG};
  float lsum[4] = {0.f, 0.f, 0.f, 0.f};

  const int nt = blockIdx.x + 1;
  for (int t = 0; t < nt; t++) {
    const int kv0 = t * 64;
    short8 kreg[4], vreg[4];
#pragma unroll
    for (int rep = 0; rep < 4; rep++) {
      kreg[rep] = *(const short8*)(Kbp + (size_t)(kv0 + rep * 16 + srow) * 1024 + sc8);
      vreg[rep] = *(const short8*)(Vbp + (size_t)(kv0 + rep * 16 + srow) * 1024 + sc8);
    }
    __syncthreads();  // all waves done reading lK/lV of tile t-1
#pragma unroll
    for (int rep = 0; rep < 4; rep++) {
      *(short8*)(lK + (rep * 16 + srow) * LKD + sc8) = kreg[rep];
#pragma unroll
      for (int j = 0; j < 8; j++)
        lV[(sc8 + j) * LVD + (rep * 16 + srow)] = (unsigned short)vreg[rep][j];
    }
    __syncthreads();

    // S = Q K^T : sacc[fc] covers kv cols fc*16 + fr
    f32x4 sacc[4] = {};
#pragma unroll
    for (int fc = 0; fc < 4; fc++)
#pragma unroll
      for (int ks = 0; ks < 4; ks++) {
        short8 bk = *(const short8*)(lK + (fc * 16 + fr) * LKD + ks * 32 + fk8);
        sacc[fc] = __builtin_amdgcn_mfma_f32_16x16x32_bf16(qf[ks], bk, sacc[fc], 0, 0, 0);
      }

    const bool diag = (t == nt - 1);
    float sv[4][4];
#pragma unroll
    for (int fc = 0; fc < 4; fc++)
#pragma unroll
      for (int jr = 0; jr < 4; jr++) {
        float x = sacc[fc][jr] * ATT_SCALE;
        if (diag && (fc * 16 + fr > w * 16 + erow + jr)) x = NEGBIG;
        sv[fc][jr] = x;
      }

    // online softmax; lane owns rows ql = w*16 + erow + jr, reduce over fr
#pragma unroll
    for (int jr = 0; jr < 4; jr++) {
      float rmax = fmaxf(fmaxf(sv[0][jr], sv[1][jr]), fmaxf(sv[2][jr], sv[3][jr]));
#pragma unroll
      for (int msk = 1; msk < 16; msk <<= 1) rmax = fmaxf(rmax, __shfl_xor(rmax, msk));
      float mnew = fmaxf(m[jr], rmax);
      float alpha = __expf(m[jr] - mnew);
      m[jr] = mnew;
      float p[4], rs = 0.f;
#pragma unroll
      for (int fc = 0; fc < 4; fc++) {
        p[fc] = __expf(sv[fc][jr] - mnew);
        rs += p[fc];
      }
#pragma unroll
      for (int msk = 1; msk < 16; msk <<= 1) rs += __shfl_xor(rs, msk);
      lsum[jr] = lsum[jr] * alpha + rs;
#pragma unroll
      for (int nf = 0; nf < 8; nf++) oacc[nf][jr] *= alpha;
      int ql = w * 16 + erow + jr;
#pragma unroll
      for (int fc = 0; fc < 4; fc++) lP[ql * LPD + fc * 16 + fr] = f2bf(p[fc]);
    }

    // O += P @ V  (A-frag = P rows (wave-private), B-frag = V^T rows = d)
#pragma unroll
    for (int kvs = 0; kvs < 2; kvs++) {
      short8 pa = *(const short8*)(lP + (w * 16 + fr) * LPD + kvs * 32 + fk8);
#pragma unroll
      for (int nf = 0; nf < 8; nf++) {
        short8 bv = *(const short8*)(lV + (nf * 16 + fr) * LVD + kvs * 32 + fk8);
        oacc[nf] = __builtin_amdgcn_mfma_f32_16x16x32_bf16(pa, bv, oacc[nf], 0, 0, 0);
      }
    }
  }

  // normalize + write O
#pragma unroll
  for (int jr = 0; jr < 4; jr++) {
    float inv = 1.0f / lsum[jr];
    unsigned short* op =
        O + (size_t)(b * 2048 + q0 + w * 16 + erow + jr) * 4096 + h * 128 + fr;
#pragma unroll
    for (int nf = 0; nf < 8; nf++) op[nf * 16] = f2bf(oacc[nf][jr] * inv);
  }
}

// ---------------------------------------------------------------------------
extern "C" void kernel_launch(void* const* d_in, const int* in_sizes, int n_in,
                              void* d_out, int out_size, void* d_ws, size_t ws_size,
                              hipStream_t stream) {
  const float* hs = (const float*)d_in[0];    // (4096, 4096) fp32
  const float* wq = (const float*)d_in[1];    // (4096, 4096) fp32
  const float* wk = (const float*)d_in[2];    // (4096, 1024) fp32
  const float* wv = (const float*)d_in[3];    // (4096, 1024) fp32
  const float* wo = (const float*)d_in[4];    // (4096, 4096) fp32
  const float* cosb = (const float*)d_in[5];  // (2048, 128) fp32
  const float* sinb = (const float*)d_in[6];  // (2048, 128) fp32
  // d_in[7] attn_mask: pure causal, applied structurally

  // Workspace (bf16 intermediates, ~134 MB). T1 holds WqT first, then WoT.
  unsigned short* ws = (unsigned short*)d_ws;
  unsigned short* T1 = ws;             // 4096x4096 (WqT, later WoT)
  unsigned short* T2 = T1 + 16777216;  // 1024x4096 (WkT)
  unsigned short* T3 = T2 + 4194304;   // 1024x4096 (WvT)
  unsigned short* Qb = T3 + 4194304;   // 4096x4096
  unsigned short* Kb = Qb + 16777216;  // 4096x1024
  unsigned short* Vb = Kb + 4194304;   // 4096x1024
  unsigned short* Ob = Vb + 4194304;   // 4096x4096

  dim3 tb(32, 8);
  transpose_f2b<<<dim3(128, 128), tb, 0, stream>>>(wq, T1, 4096, 4096);
  transpose_f2b<<<dim3(32, 128), tb, 0, stream>>>(wk, T2, 4096, 1024);
  transpose_f2b<<<dim3(32, 128), tb, 0, stream>>>(wv, T3, 4096, 1024);

  gemm_bt<1, 0><<<dim3(32, 32), 256, 0, stream>>>(hs, T1, Qb, 4096, 4096, 4096);
  gemm_bt<1, 0><<<dim3(32, 8), 256, 0, stream>>>(hs, T2, Kb, 4096, 1024, 4096);
  gemm_bt<1, 0><<<dim3(32, 8), 256, 0, stream>>>(hs, T3, Vb, 4096, 1024, 4096);

  // T1 is free now: stage WoT into it
  transpose_f2b<<<dim3(128, 128), tb, 0, stream>>>(wo, T1, 4096, 4096);

  rope_kernel<<<4096, 256, 0, stream>>>(Qb, cosb, sinb, 5, 4096 * 32 * 8);
  rope_kernel<<<1024, 256, 0, stream>>>(Kb, cosb, sinb, 3, 4096 * 8 * 8);

  flash_attn<<<dim3(32, 32, 2), 256, 0, stream>>>(Qb, Kb, Vb, Ob);

  gemm_bt<0, 1><<<dim3(32, 32), 256, 0, stream>>>(Ob, T1, (float*)d_out, 4096, 4096, 4096);
}

// Round 4
// 766.008 us; speedup vs baseline: 1.8049x; 1.8049x over previous
//
#include <hip/hip_runtime.h>

typedef __attribute__((ext_vector_type(8))) short short8;
typedef __attribute__((ext_vector_type(4))) float f32x4;

__device__ __forceinline__ float bf2f(unsigned short u) {
  unsigned int x = ((unsigned int)u) << 16;
  float f;
  __builtin_memcpy(&f, &x, 4);
  return f;
}
__device__ __forceinline__ unsigned short f2bf(float f) {
  unsigned int x;
  __builtin_memcpy(&x, &f, 4);
  unsigned int r = (x + 0x7FFFu + ((x >> 16) & 1u)) >> 16;
  return (unsigned short)r;
}
// load 8 consecutive fp32, round to bf16
__device__ __forceinline__ short8 ld8_f32(const float* p) {
  f32x4 x = *(const f32x4*)p;
  f32x4 y = *(const f32x4*)(p + 4);
  short8 r;
  r[0] = (short)f2bf(x[0]); r[1] = (short)f2bf(x[1]);
  r[2] = (short)f2bf(x[2]); r[3] = (short)f2bf(x[3]);
  r[4] = (short)f2bf(y[0]); r[5] = (short)f2bf(y[1]);
  r[6] = (short)f2bf(y[2]); r[7] = (short)f2bf(y[3]);
  return r;
}

__device__ __forceinline__ void async16(unsigned short* lds, const unsigned short* g) {
  __builtin_amdgcn_global_load_lds(
      (const __attribute__((address_space(1))) void*)g,
      (__attribute__((address_space(3))) void*)lds, 16, 0, 0);
}

// ---------------------------------------------------------------------------
// Downcast fp32 -> bf16, 8 elems/thread
// ---------------------------------------------------------------------------
__global__ void downcast_f2b(const float* __restrict__ in,
                             unsigned short* __restrict__ out, int n8) {
  int i = blockIdx.x * 256 + threadIdx.x;
  if (i >= n8) return;
  *(short8*)(out + (size_t)i * 8) = ld8_f32(in + (size_t)i * 8);
}

// ---------------------------------------------------------------------------
// Transpose + downcast: in fp32 (R x C) -> out bf16 (C x R)
// ---------------------------------------------------------------------------
__global__ void transpose_f2b(const float* __restrict__ in,
                              unsigned short* __restrict__ out, int R, int Ccols) {
  __shared__ unsigned short tile[32][33];
  const int c0 = blockIdx.x * 32;
  const int r0 = blockIdx.y * 32;
  const int tx = threadIdx.x, ty = threadIdx.y;
#pragma unroll
  for (int i = 0; i < 32; i += 8)
    tile[ty + i][tx] = f2bf(in[(size_t)(r0 + ty + i) * Ccols + (c0 + tx)]);
  __syncthreads();
#pragma unroll
  for (int i = 0; i < 32; i += 8)
    out[(size_t)(c0 + ty + i) * R + (r0 + tx)] = tile[tx][ty + i];
}

// ---------------------------------------------------------------------------
// GEMM: C (MxN) = A (MxK) @ BT^T. A,BT bf16; fp32 accum. m97 structure:
// 128x128 tile, BK=32, 4 waves, linear LDS, global_load_lds width-16 staging.
// CF32: C fp32 else bf16.
// ---------------------------------------------------------------------------
template <int CF32>
__global__ __launch_bounds__(256, 2) void gemm_bt(
    const unsigned short* __restrict__ A, const unsigned short* __restrict__ BT,
    void* __restrict__ Cp, int M, int N, int K) {
  alignas(16) __shared__ unsigned short lA[128 * 32];
  alignas(16) __shared__ unsigned short lB[128 * 32];
  const int tid = threadIdx.x;
  const int lane = tid & 63;
  const int wid = tid >> 6;
  const int wr = wid >> 1, wc = wid & 1;
  const int bm = blockIdx.x * 128;
  const int bn = blockIdx.y * 128;

  const int ar = tid >> 2;        // row within 64-row half
  const int ac = (tid & 3) << 3;  // col 0,8,16,24
  const unsigned short* aS0 = A + (size_t)(bm + ar) * K + ac;
  const unsigned short* aS1 = A + (size_t)(bm + 64 + ar) * K + ac;
  const unsigned short* bS0 = BT + (size_t)(bn + ar) * K + ac;
  const unsigned short* bS1 = BT + (size_t)(bn + 64 + ar) * K + ac;
  unsigned short* dA0 = lA + tid * 8;
  unsigned short* dA1 = lA + 2048 + tid * 8;
  unsigned short* dB0 = lB + tid * 8;
  unsigned short* dB1 = lB + 2048 + tid * 8;

  const int fr = lane & 15;         // fragment m/n index
  const int fk = (lane >> 4) << 3;  // k offset (8 contiguous)

  f32x4 acc[4][4] = {};

  for (int kt = 0; kt < K; kt += 32) {
    async16(dA0, aS0 + kt);
    async16(dA1, aS1 + kt);
    async16(dB0, bS0 + kt);
    async16(dB1, bS1 + kt);
    __syncthreads();  // drains vmcnt -> LDS tile ready
    short8 af[4], bfr[4];
#pragma unroll
    for (int i = 0; i < 4; i++) {
      af[i] = *(const short8*)(lA + (wr * 64 + i * 16 + fr) * 32 + fk);
      bfr[i] = *(const short8*)(lB + (wc * 64 + i * 16 + fr) * 32 + fk);
    }
#pragma unroll
    for (int i = 0; i < 4; i++)
#pragma unroll
      for (int j = 0; j < 4; j++)
        acc[i][j] = __builtin_amdgcn_mfma_f32_16x16x32_bf16(af[i], bfr[j], acc[i][j], 0, 0, 0);
    __syncthreads();  // all waves done reading before next tile's async writes
  }

  // C/D layout: col = lane&15, row = (lane>>4)*4 + r
  const int er = (lane >> 4) << 2;
#pragma unroll
  for (int i = 0; i < 4; i++) {
#pragma unroll
    for (int j = 0; j < 4; j++) {
      int row = bm + wr * 64 + i * 16 + er;
      int col = bn + wc * 64 + j * 16 + fr;
#pragma unroll
      for (int r = 0; r < 4; r++) {
        if constexpr (CF32)
          ((float*)Cp)[(size_t)(row + r) * N + col] = acc[i][j][r];
        else
          ((unsigned short*)Cp)[(size_t)(row + r) * N + col] = f2bf(acc[i][j][r]);
      }
    }
  }
}

// ---------------------------------------------------------------------------
// RoPE in-place on bf16 buf (4096 tokens x nh*128). cos/sin fp32 (2048 x 128).
// cos[d+64]==cos[d], sin[d+64]==sin[d] (emb = concat(freqs,freqs)).
// ---------------------------------------------------------------------------
__global__ void rope_kernel(unsigned short* __restrict__ buf,
                            const float* __restrict__ cosb,
                            const float* __restrict__ sinb,
                            int nh_shift, int total) {
  int gid = blockIdx.x * 256 + threadIdx.x;
  if (gid >= total) return;
  int dblk = gid & 7;
  int u = gid >> 3;
  int head = u & ((1 << nh_shift) - 1);
  int token = u >> nh_shift;
  int s = token & 2047;
  int d0 = dblk << 3;
  unsigned short* p0 = buf + ((size_t)token << (7 + nh_shift)) + (head << 7) + d0;
  unsigned short* p1 = p0 + 64;
  const float* cp = cosb + s * 128 + d0;
  const float* sp = sinb + s * 128 + d0;
  short8 a = *(const short8*)p0;
  short8 bq = *(const short8*)p1;
  f32x4 c0 = *(const f32x4*)cp, c1 = *(const f32x4*)(cp + 4);
  f32x4 s0 = *(const f32x4*)sp, s1 = *(const f32x4*)(sp + 4);
  short8 o0, o1;
#pragma unroll
  for (int j = 0; j < 8; j++) {
    float x0 = bf2f((unsigned short)a[j]);
    float x1 = bf2f((unsigned short)bq[j]);
    float c = (j < 4) ? c0[j & 3] : c1[j & 3];
    float sn = (j < 4) ? s0[j & 3] : s1[j & 3];
    o0[j] = (short)f2bf(x0 * c - x1 * sn);
    o1[j] = (short)f2bf(x1 * c + x0 * sn);
  }
  *(short8*)p0 = o0;
  *(short8*)p1 = o1;
}

// ---------------------------------------------------------------------------
// Flash attention, causal, GQA (grp=4). 256 thr / 4 waves. Block handles
// q-tiles x and 31-x sequentially (balanced: 33 tile-iters per block).
// V scatter writes bank-rotated (2-way, was 16-way). Next K/V tile
// prefetched into regs before compute.
// ---------------------------------------------------------------------------
#define LKD 136  // lK row stride (shorts): rows kv (64) x cols d (128)
#define LVD 72   // lV row stride: rows d (128) x cols kv (64)  (V transposed)
#define LPD 72   // lP row stride: rows q (64) x cols kv (64)
#define ATT_SCALE 0.08838834764831845f
#define NEGBIG -30000.0f

__global__ __launch_bounds__(256, 2) void flash_attn(
    const unsigned short* __restrict__ Q, const unsigned short* __restrict__ K,
    const unsigned short* __restrict__ V, unsigned short* __restrict__ O) {
  alignas(16) __shared__ unsigned short lK[64 * LKD];
  alignas(16) __shared__ unsigned short lV[128 * LVD];
  alignas(16) __shared__ unsigned short lP[64 * LPD];

  const int tid = threadIdx.x;
  const int lane = tid & 63;
  const int w = tid >> 6;
  const int b = blockIdx.z;
  const int h = blockIdx.y;
  const int xa = blockIdx.x;  // 0..15
  const int kvh = h >> 2;

  const int fr = lane & 15;
  const int fk8 = (lane >> 4) << 3;
  const int erow = (lane >> 4) << 2;

  const int srow = tid >> 4;        // 0..15
  const int sc8 = (tid & 15) << 3;  // 0..120 (d chunk)
  const int rot = tid & 15;         // bank-rotation key for V scatter
  const unsigned short* Kbp = K + (size_t)(b * 2048) * 1024 + kvh * 128;
  const unsigned short* Vbp = V + (size_t)(b * 2048) * 1024 + kvh * 128;

  for (int pass = 0; pass < 2; pass++) {
    const int x = pass ? (31 - xa) : xa;
    const int q0 = x * 64;
    const int nt = x + 1;

    // Q fragments: row = q0 + w*16 + fr, k = ks*32 + fk8 + [0..8)
    short8 qf[4];
    {
      const unsigned short* qb =
          Q + (size_t)(b * 2048 + q0 + w * 16 + fr) * 4096 + h * 128 + fk8;
#pragma unroll
      for (int ks = 0; ks < 4; ks++) qf[ks] = *(const short8*)(qb + ks * 32);
    }

    f32x4 oacc[8] = {};
    float m[4] = {NEGBIG, NEGBIG, NEGBIG, NEGBIG};
    float lsum[4] = {0.f, 0.f, 0.f, 0.f};

    // prefetch tile 0
    short8 kreg[4], vreg[4];
#pragma unroll
    for (int rep = 0; rep < 4; rep++) {
      kreg[rep] = *(const short8*)(Kbp + (size_t)(rep * 16 + srow) * 1024 + sc8);
      vreg[rep] = *(const short8*)(Vbp + (size_t)(rep * 16 + srow) * 1024 + sc8);
    }

    for (int t = 0; t < nt; t++) {
      __syncthreads();  // all waves done reading lK/lV of previous tile
#pragma unroll
      for (int rep = 0; rep < 4; rep++) {
        *(short8*)(lK + (rep * 16 + srow) * LKD + sc8) = kreg[rep];
        int kv = rep * 16 + srow;
#pragma unroll
        for (int jj = 0; jj < 8; jj++) {
          int j = (jj + rot) & 7;  // rotate: 16-way -> 2-way bank conflict
          lV[(size_t)(sc8 + j) * LVD + kv] = (unsigned short)vreg[rep][j];
        }
      }
      __syncthreads();

      // prefetch next tile into regs (hidden under compute below)
      if (t + 1 < nt) {
        const int kv1 = (t + 1) * 64;
#pragma unroll
        for (int rep = 0; rep < 4; rep++) {
          kreg[rep] = *(const short8*)(Kbp + (size_t)(kv1 + rep * 16 + srow) * 1024 + sc8);
          vreg[rep] = *(const short8*)(Vbp + (size_t)(kv1 + rep * 16 + srow) * 1024 + sc8);
        }
      }

      // S = Q K^T : sacc[fc] covers kv cols fc*16 + fr
      f32x4 sacc[4] = {};
#pragma unroll
      for (int fc = 0; fc < 4; fc++)
#pragma unroll
        for (int ks = 0; ks < 4; ks++) {
          short8 bk = *(const short8*)(lK + (fc * 16 + fr) * LKD + ks * 32 + fk8);
          sacc[fc] = __builtin_amdgcn_mfma_f32_16x16x32_bf16(qf[ks], bk, sacc[fc], 0, 0, 0);
        }

      const bool diag = (t == nt - 1);
      float sv[4][4];
#pragma unroll
      for (int fc = 0; fc < 4; fc++)
#pragma unroll
        for (int jr = 0; jr < 4; jr++) {
          float xx = sacc[fc][jr] * ATT_SCALE;
          if (diag && (fc * 16 + fr > w * 16 + erow + jr)) xx = NEGBIG;
          sv[fc][jr] = xx;
        }

      // online softmax; lane owns rows ql = w*16 + erow + jr, reduce over fr
#pragma unroll
      for (int jr = 0; jr < 4; jr++) {
        float rmax = fmaxf(fmaxf(sv[0][jr], sv[1][jr]), fmaxf(sv[2][jr], sv[3][jr]));
#pragma unroll
        for (int msk = 1; msk < 16; msk <<= 1) rmax = fmaxf(rmax, __shfl_xor(rmax, msk));
        float mnew = fmaxf(m[jr], rmax);
        float alpha = __expf(m[jr] - mnew);
        m[jr] = mnew;
        float p[4], rs = 0.f;
#pragma unroll
        for (int fc = 0; fc < 4; fc++) {
          p[fc] = __expf(sv[fc][jr] - mnew);
          rs += p[fc];
        }
#pragma unroll
        for (int msk = 1; msk < 16; msk <<= 1) rs += __shfl_xor(rs, msk);
        lsum[jr] = lsum[jr] * alpha + rs;
#pragma unroll
        for (int nf = 0; nf < 8; nf++) oacc[nf][jr] *= alpha;
        int ql = w * 16 + erow + jr;
#pragma unroll
        for (int fc = 0; fc < 4; fc++) lP[ql * LPD + fc * 16 + fr] = f2bf(p[fc]);
      }

      // O += P @ V  (A-frag = P rows (wave-private), B-frag = V^T rows = d)
#pragma unroll
      for (int kvs = 0; kvs < 2; kvs++) {
        short8 pa = *(const short8*)(lP + (w * 16 + fr) * LPD + kvs * 32 + fk8);
#pragma unroll
        for (int nf = 0; nf < 8; nf++) {
          short8 bv = *(const short8*)(lV + (nf * 16 + fr) * LVD + kvs * 32 + fk8);
          oacc[nf] = __builtin_amdgcn_mfma_f32_16x16x32_bf16(pa, bv, oacc[nf], 0, 0, 0);
        }
      }
    }

    // normalize + write O for this pass
#pragma unroll
    for (int jr = 0; jr < 4; jr++) {
      float inv = 1.0f / lsum[jr];
      unsigned short* op =
          O + (size_t)(b * 2048 + q0 + w * 16 + erow + jr) * 4096 + h * 128 + fr;
#pragma unroll
      for (int nf = 0; nf < 8; nf++) op[nf * 16] = f2bf(oacc[nf][jr] * inv);
    }
  }
}

// ---------------------------------------------------------------------------
extern "C" void kernel_launch(void* const* d_in, const int* in_sizes, int n_in,
                              void* d_out, int out_size, void* d_ws, size_t ws_size,
                              hipStream_t stream) {
  const float* hs = (const float*)d_in[0];    // (4096, 4096) fp32
  const float* wq = (const float*)d_in[1];    // (4096, 4096) fp32
  const float* wk = (const float*)d_in[2];    // (4096, 1024) fp32
  const float* wv = (const float*)d_in[3];    // (4096, 1024) fp32
  const float* wo = (const float*)d_in[4];    // (4096, 4096) fp32
  const float* cosb = (const float*)d_in[5];  // (2048, 128) fp32
  const float* sinb = (const float*)d_in[6];  // (2048, 128) fp32
  // d_in[7] attn_mask: pure causal, applied structurally

  // Workspace (bf16 intermediates). T1 holds WqT first, then WoT.
  unsigned short* ws = (unsigned short*)d_ws;
  unsigned short* T1 = ws;             // 4096x4096 (WqT, later WoT)
  unsigned short* T2 = T1 + 16777216;  // 1024x4096 (WkT)
  unsigned short* T3 = T2 + 4194304;   // 1024x4096 (WvT)
  unsigned short* Qb = T3 + 4194304;   // 4096x4096
  unsigned short* Kb = Qb + 16777216;  // 4096x1024
  unsigned short* Vb = Kb + 4194304;   // 4096x1024
  unsigned short* Ob = Vb + 4194304;   // 4096x4096

  // hs downcast lives in d_out's first half (67 MB fp32 buffer; consumed by
  // the QKV gemms before the final O-gemm overwrites d_out).
  unsigned short* hsb = (unsigned short*)d_out;  // 4096x4096 bf16

  dim3 tb(32, 8);
  downcast_f2b<<<8192, 256, 0, stream>>>(hs, hsb, 2097152);
  transpose_f2b<<<dim3(128, 128), tb, 0, stream>>>(wq, T1, 4096, 4096);
  transpose_f2b<<<dim3(32, 128), tb, 0, stream>>>(wk, T2, 4096, 1024);
  transpose_f2b<<<dim3(32, 128), tb, 0, stream>>>(wv, T3, 4096, 1024);

  gemm_bt<0><<<dim3(32, 32), 256, 0, stream>>>(hsb, T1, Qb, 4096, 4096, 4096);
  gemm_bt<0><<<dim3(32, 8), 256, 0, stream>>>(hsb, T2, Kb, 4096, 1024, 4096);
  gemm_bt<0><<<dim3(32, 8), 256, 0, stream>>>(hsb, T3, Vb, 4096, 1024, 4096);

  // T1 is free now: stage WoT into it
  transpose_f2b<<<dim3(128, 128), tb, 0, stream>>>(wo, T1, 4096, 4096);

  rope_kernel<<<4096, 256, 0, stream>>>(Qb, cosb, sinb, 5, 4096 * 32 * 8);
  rope_kernel<<<1024, 256, 0, stream>>>(Kb, cosb, sinb, 3, 4096 * 8 * 8);

  flash_attn<<<dim3(16, 32, 2), 256, 0, stream>>>(Qb, Kb, Vb, Ob);

  gemm_bt<1><<<dim3(32, 32), 256, 0, stream>>>(Ob, T1, (float*)d_out, 4096, 4096, 4096);
}

// Round 5
// 642.169 us; speedup vs baseline: 2.1529x; 1.1928x over previous
//
#include <hip/hip_runtime.h>

typedef __attribute__((ext_vector_type(8))) short short8;
typedef __attribute__((ext_vector_type(4))) float f32x4;
typedef __attribute__((ext_vector_type(4))) int int4v;

__device__ __forceinline__ float bf2f(unsigned short u) {
  unsigned int x = ((unsigned int)u) << 16;
  float f;
  __builtin_memcpy(&f, &x, 4);
  return f;
}
__device__ __forceinline__ unsigned short f2bf(float f) {
  unsigned int x;
  __builtin_memcpy(&x, &f, 4);
  unsigned int r = (x + 0x7FFFu + ((x >> 16) & 1u)) >> 16;
  return (unsigned short)r;
}
__device__ __forceinline__ unsigned int cvtpk_bf16(float lo, float hi) {
  unsigned int r;
  asm("v_cvt_pk_bf16_f32 %0, %1, %2" : "=v"(r) : "v"(lo), "v"(hi));
  return r;
}
__device__ __forceinline__ int4v s8_to_i4(short8 v) {
  int4v r;
  __builtin_memcpy(&r, &v, 16);
  return r;
}
__device__ __forceinline__ short8 i4_to_s8(int4v v) {
  short8 r;
  __builtin_memcpy(&r, &v, 16);
  return r;
}
// load 8 consecutive fp32, round to bf16
__device__ __forceinline__ short8 ld8_f32(const float* p) {
  f32x4 x = *(const f32x4*)p;
  f32x4 y = *(const f32x4*)(p + 4);
  short8 r;
  r[0] = (short)f2bf(x[0]); r[1] = (short)f2bf(x[1]);
  r[2] = (short)f2bf(x[2]); r[3] = (short)f2bf(x[3]);
  r[4] = (short)f2bf(y[0]); r[5] = (short)f2bf(y[1]);
  r[6] = (short)f2bf(y[2]); r[7] = (short)f2bf(y[3]);
  return r;
}

__device__ __forceinline__ void async16(unsigned short* lds, const unsigned short* g) {
  __builtin_amdgcn_global_load_lds(
      (const __attribute__((address_space(1))) void*)g,
      (__attribute__((address_space(3))) void*)lds, 16, 0, 0);
}

// ---------------------------------------------------------------------------
__global__ void downcast_f2b(const float* __restrict__ in,
                             unsigned short* __restrict__ out, int n8) {
  int i = blockIdx.x * 256 + threadIdx.x;
  if (i >= n8) return;
  *(short8*)(out + (size_t)i * 8) = ld8_f32(in + (size_t)i * 8);
}

// ---------------------------------------------------------------------------
__global__ void transpose_f2b(const float* __restrict__ in,
                              unsigned short* __restrict__ out, int R, int Ccols) {
  __shared__ unsigned short tile[32][33];
  const int c0 = blockIdx.x * 32;
  const int r0 = blockIdx.y * 32;
  const int tx = threadIdx.x, ty = threadIdx.y;
#pragma unroll
  for (int i = 0; i < 32; i += 8)
    tile[ty + i][tx] = f2bf(in[(size_t)(r0 + ty + i) * Ccols + (c0 + tx)]);
  __syncthreads();
#pragma unroll
  for (int i = 0; i < 32; i += 8)
    out[(size_t)(c0 + ty + i) * R + (r0 + tx)] = tile[tx][ty + i];
}

// ---------------------------------------------------------------------------
// GEMM: C (MxN) = A (MxK) @ BT^T. A,BT bf16; fp32 accum. m97 structure.
// ---------------------------------------------------------------------------
template <int CF32>
__global__ __launch_bounds__(256, 2) void gemm_bt(
    const unsigned short* __restrict__ A, const unsigned short* __restrict__ BT,
    void* __restrict__ Cp, int M, int N, int K) {
  alignas(16) __shared__ unsigned short lA[128 * 32];
  alignas(16) __shared__ unsigned short lB[128 * 32];
  const int tid = threadIdx.x;
  const int lane = tid & 63;
  const int wid = tid >> 6;
  const int wr = wid >> 1, wc = wid & 1;
  const int bm = blockIdx.x * 128;
  const int bn = blockIdx.y * 128;

  const int ar = tid >> 2;
  const int ac = (tid & 3) << 3;
  const unsigned short* aS0 = A + (size_t)(bm + ar) * K + ac;
  const unsigned short* aS1 = A + (size_t)(bm + 64 + ar) * K + ac;
  const unsigned short* bS0 = BT + (size_t)(bn + ar) * K + ac;
  const unsigned short* bS1 = BT + (size_t)(bn + 64 + ar) * K + ac;
  unsigned short* dA0 = lA + tid * 8;
  unsigned short* dA1 = lA + 2048 + tid * 8;
  unsigned short* dB0 = lB + tid * 8;
  unsigned short* dB1 = lB + 2048 + tid * 8;

  const int fr = lane & 15;
  const int fk = (lane >> 4) << 3;

  f32x4 acc[4][4] = {};

  for (int kt = 0; kt < K; kt += 32) {
    async16(dA0, aS0 + kt);
    async16(dA1, aS1 + kt);
    async16(dB0, bS0 + kt);
    async16(dB1, bS1 + kt);
    __syncthreads();
    short8 af[4], bfr[4];
#pragma unroll
    for (int i = 0; i < 4; i++) {
      af[i] = *(const short8*)(lA + (wr * 64 + i * 16 + fr) * 32 + fk);
      bfr[i] = *(const short8*)(lB + (wc * 64 + i * 16 + fr) * 32 + fk);
    }
#pragma unroll
    for (int i = 0; i < 4; i++)
#pragma unroll
      for (int j = 0; j < 4; j++)
        acc[i][j] = __builtin_amdgcn_mfma_f32_16x16x32_bf16(af[i], bfr[j], acc[i][j], 0, 0, 0);
    __syncthreads();
  }

  const int er = (lane >> 4) << 2;
#pragma unroll
  for (int i = 0; i < 4; i++) {
#pragma unroll
    for (int j = 0; j < 4; j++) {
      int row = bm + wr * 64 + i * 16 + er;
      int col = bn + wc * 64 + j * 16 + fr;
#pragma unroll
      for (int r = 0; r < 4; r++) {
        if constexpr (CF32)
          ((float*)Cp)[(size_t)(row + r) * N + col] = acc[i][j][r];
        else
          ((unsigned short*)Cp)[(size_t)(row + r) * N + col] = f2bf(acc[i][j][r]);
      }
    }
  }
}

// ---------------------------------------------------------------------------
// RoPE in-place on bf16 buf; row stride parametrized. cos/sin fp32 (2048x128).
// ---------------------------------------------------------------------------
__global__ void rope_kernel(unsigned short* __restrict__ buf,
                            const float* __restrict__ cosb,
                            const float* __restrict__ sinb,
                            int nh_shift, int rstride, int total) {
  int gid = blockIdx.x * 256 + threadIdx.x;
  if (gid >= total) return;
  int dblk = gid & 7;
  int u = gid >> 3;
  int head = u & ((1 << nh_shift) - 1);
  int token = u >> nh_shift;
  int s = token & 2047;
  int d0 = dblk << 3;
  unsigned short* p0 = buf + (size_t)token * rstride + (head << 7) + d0;
  unsigned short* p1 = p0 + 64;
  const float* cp = cosb + s * 128 + d0;
  const float* sp = sinb + s * 128 + d0;
  short8 a = *(const short8*)p0;
  short8 bq = *(const short8*)p1;
  f32x4 c0 = *(const f32x4*)cp, c1 = *(const f32x4*)(cp + 4);
  f32x4 s0 = *(const f32x4*)sp, s1 = *(const f32x4*)(sp + 4);
  short8 o0, o1;
#pragma unroll
  for (int j = 0; j < 8; j++) {
    float x0 = bf2f((unsigned short)a[j]);
    float x1 = bf2f((unsigned short)bq[j]);
    float c = (j < 4) ? c0[j & 3] : c1[j & 3];
    float sn = (j < 4) ? s0[j & 3] : s1[j & 3];
    o0[j] = (short)f2bf(x0 * c - x1 * sn);
    o1[j] = (short)f2bf(x1 * c + x0 * sn);
  }
  *(short8*)p0 = o0;
  *(short8*)p1 = o1;
}

// ---------------------------------------------------------------------------
// Flash attention v2: causal, GQA. QBLK=128 (4 waves x 32 q rows), KVBLK=64.
// Swapped QK^T (mfma(K,Q)) -> lane owns a full q-row: softmax + P fully
// in-register (cvt_pk_bf16 + shfl redistribution). V staged as packed kv-pair
// u32s (4 ds_write_b32/thread/tile). K/V from combined KV buffer (stride 2048).
// ---------------------------------------------------------------------------
#define LKD 136  // lK row stride in shorts
#define LVW 36   // lV row stride in u32 words
#define ATT_SCALE 0.08838834764831845f
#define NEGBIG -30000.0f

__global__ __launch_bounds__(256, 2) void flash_attn(
    const unsigned short* __restrict__ Q, const unsigned short* __restrict__ KV,
    unsigned short* __restrict__ O) {
  alignas(16) __shared__ unsigned short lK[64 * LKD];
  alignas(16) __shared__ unsigned int lV[128 * LVW];

  const int tid = threadIdx.x;
  const int lane = tid & 63;
  const int w = tid >> 6;
  const int b = blockIdx.z;
  const int h = blockIdx.y;
  const int xa = blockIdx.x;  // 0..7
  const int kvh = h >> 2;

  const int fr = lane & 15;
  const int hi = lane >> 4;
  const int fk8 = hi << 3;
  const int hi4 = hi << 2;

  const int srow = tid >> 4;        // 0..15
  const int sc8 = (tid & 15) << 3;  // 0..120
  const int parity = srow & 1;

  const unsigned short* Kbp = KV + (size_t)(b * 2048) * 2048 + kvh * 128;
  const unsigned short* Vbp = Kbp + 1024;

  for (int pass = 0; pass < 2; pass++) {
    const int x = pass ? (15 - xa) : xa;
    const int q0 = x * 128;
    const int nt = 2 * x + 2;

    // Q fragments: qf[qsub][ks], row q = q0 + w*32 + qsub*16 + fr
    short8 qf[2][4];
#pragma unroll
    for (int qsub = 0; qsub < 2; qsub++) {
      const unsigned short* qb =
          Q + (size_t)(b * 2048 + q0 + w * 32 + qsub * 16 + fr) * 4096 + h * 128 + fk8;
#pragma unroll
      for (int ks = 0; ks < 4; ks++) qf[qsub][ks] = *(const short8*)(qb + ks * 32);
    }

    f32x4 oacc[2][8] = {};
    float m2[2] = {NEGBIG, NEGBIG};
    float ls[2] = {0.f, 0.f};

    // prefetch tile 0
    short8 kreg[4], vreg[4];
#pragma unroll
    for (int rep = 0; rep < 4; rep++) {
      kreg[rep] = *(const short8*)(Kbp + (size_t)(rep * 16 + srow) * 2048 + sc8);
      vreg[rep] = *(const short8*)(Vbp + (size_t)(rep * 16 + srow) * 2048 + sc8);
    }

    for (int t = 0; t < nt; t++) {
      __syncthreads();  // waves done reading prev tile's LDS
      // stage K
#pragma unroll
      for (int rep = 0; rep < 4; rep++)
        *(short8*)(lK + (rep * 16 + srow) * LKD + sc8) = kreg[rep];
      // stage V as packed kv-pairs: lV[d][kvpair] = (V[2p][d], V[2p+1][d])
#pragma unroll
      for (int rep = 0; rep < 4; rep++) {
        int4v own = s8_to_i4(vreg[rep]);
        int4v oth;
#pragma unroll
        for (int q = 0; q < 4; q++) oth[q] = __shfl_xor(own[q], 16);
        unsigned int oA = parity ? (unsigned)own[2] : (unsigned)own[0];
        unsigned int oB = parity ? (unsigned)own[3] : (unsigned)own[1];
        unsigned int tA = parity ? (unsigned)oth[2] : (unsigned)oth[0];
        unsigned int tB = parity ? (unsigned)oth[3] : (unsigned)oth[1];
        unsigned int evA = parity ? tA : oA, odA = parity ? oA : tA;
        unsigned int evB = parity ? tB : oB, odB = parity ? oB : tB;
        int d0 = sc8 + (parity << 2);
        int kvp = rep * 8 + (srow >> 1);
        lV[(d0 + 0) * LVW + kvp] = (evA & 0xFFFFu) | (odA << 16);
        lV[(d0 + 1) * LVW + kvp] = (evA >> 16) | (odA & 0xFFFF0000u);
        lV[(d0 + 2) * LVW + kvp] = (evB & 0xFFFFu) | (odB << 16);
        lV[(d0 + 3) * LVW + kvp] = (evB >> 16) | (odB & 0xFFFF0000u);
      }
      __syncthreads();

      // prefetch next tile
      if (t + 1 < nt) {
        const int kv1 = (t + 1) * 64;
#pragma unroll
        for (int rep = 0; rep < 4; rep++) {
          kreg[rep] = *(const short8*)(Kbp + (size_t)(kv1 + rep * 16 + srow) * 2048 + sc8);
          vreg[rep] = *(const short8*)(Vbp + (size_t)(kv1 + rep * 16 + srow) * 2048 + sc8);
        }
      }

      // S^T = mfma(K, Q): lane (fr,hi) holds S[q=fr][kv = fc*16 + hi*4 + r]
      f32x4 sacc[2][4] = {};
      __builtin_amdgcn_s_setprio(1);
#pragma unroll
      for (int fc = 0; fc < 4; fc++)
#pragma unroll
        for (int ks = 0; ks < 4; ks++) {
          short8 bk = *(const short8*)(lK + (fc * 16 + fr) * LKD + ks * 32 + fk8);
          sacc[0][fc] = __builtin_amdgcn_mfma_f32_16x16x32_bf16(bk, qf[0][ks], sacc[0][fc], 0, 0, 0);
          sacc[1][fc] = __builtin_amdgcn_mfma_f32_16x16x32_bf16(bk, qf[1][ks], sacc[1][fc], 0, 0, 0);
        }
      __builtin_amdgcn_s_setprio(0);

      const bool diag = (t >= nt - 2);
      const int kvb = t * 64;
      unsigned int pk[2][4][2];

#pragma unroll
      for (int qsub = 0; qsub < 2; qsub++) {
        const int q = q0 + w * 32 + qsub * 16 + fr;
        float sv[4][4];
#pragma unroll
        for (int fc = 0; fc < 4; fc++)
#pragma unroll
          for (int r = 0; r < 4; r++) {
            float xx = sacc[qsub][fc][r] * ATT_SCALE;
            if (diag && (kvb + fc * 16 + hi4 + r > q)) xx = NEGBIG;
            sv[fc][r] = xx;
          }
        // row max (lane holds 16 of 64; other 48 in the 3 sibling hi-lanes)
        float mx = sv[0][0];
#pragma unroll
        for (int fc = 0; fc < 4; fc++)
#pragma unroll
          for (int r = 0; r < 4; r++) mx = fmaxf(mx, sv[fc][r]);
        mx = fmaxf(mx, __shfl_xor(mx, 16));
        mx = fmaxf(mx, __shfl_xor(mx, 32));
        float mnew = fmaxf(m2[qsub], mx);
        float alpha = __expf(m2[qsub] - mnew);
        m2[qsub] = mnew;
        float rs = 0.f;
        float p[4][4];
#pragma unroll
        for (int fc = 0; fc < 4; fc++)
#pragma unroll
          for (int r = 0; r < 4; r++) {
            p[fc][r] = __expf(sv[fc][r] - mnew);
            rs += p[fc][r];
          }
        rs += __shfl_xor(rs, 16);
        rs += __shfl_xor(rs, 32);
        ls[qsub] = ls[qsub] * alpha + rs;
#pragma unroll
        for (int fc = 0; fc < 4; fc++) {
          pk[qsub][fc][0] = cvtpk_bf16(p[fc][0], p[fc][1]);
          pk[qsub][fc][1] = cvtpk_bf16(p[fc][2], p[fc][3]);
        }
        // rescale oacc: row q_local = hi*4 + r needs alpha of owner lane (hi*4+r)
        f32x4 av;
#pragma unroll
        for (int r = 0; r < 4; r++) av[r] = __shfl(alpha, hi4 + r);
#pragma unroll
        for (int nf = 0; nf < 8; nf++) oacc[qsub][nf] *= av;
      }

      // PV: af[qsub] built by redistributing pk across the 4 hi-lanes
      const int src0 = fr + ((hi & 1) << 5);
      const int src1 = src0 + 16;
#pragma unroll
      for (int kvs = 0; kvs < 2; kvs++) {
        unsigned int aw[2][4];
#pragma unroll
        for (int qsub = 0; qsub < 2; qsub++) {
#pragma unroll
          for (int jj = 0; jj < 4; jj++) {
            int src = (jj < 2) ? src0 : src1;
            int rr = jj & 1;
            unsigned int y0 = (unsigned)__shfl((int)pk[qsub][kvs * 2][rr], src);
            unsigned int y1 = (unsigned)__shfl((int)pk[qsub][kvs * 2 + 1][rr], src);
            aw[qsub][jj] = (hi >> 1) ? y1 : y0;
          }
        }
        int4v a0i = {(int)aw[0][0], (int)aw[0][1], (int)aw[0][2], (int)aw[0][3]};
        int4v a1i = {(int)aw[1][0], (int)aw[1][1], (int)aw[1][2], (int)aw[1][3]};
        short8 af0 = i4_to_s8(a0i), af1 = i4_to_s8(a1i);
        __builtin_amdgcn_s_setprio(1);
#pragma unroll
        for (int nf = 0; nf < 8; nf++) {
          int4v bvw = *(const int4v*)(lV + (nf * 16 + fr) * LVW + kvs * 16 + hi4);
          short8 bv = i4_to_s8(bvw);
          oacc[0][nf] = __builtin_amdgcn_mfma_f32_16x16x32_bf16(af0, bv, oacc[0][nf], 0, 0, 0);
          oacc[1][nf] = __builtin_amdgcn_mfma_f32_16x16x32_bf16(af1, bv, oacc[1][nf], 0, 0, 0);
        }
        __builtin_amdgcn_s_setprio(0);
      }
    }

    // epilogue: normalize + store (O rows q = q0 + w*32 + qsub*16 + hi*4 + r)
#pragma unroll
    for (int qsub = 0; qsub < 2; qsub++) {
      f32x4 iv;
#pragma unroll
      for (int r = 0; r < 4; r++) iv[r] = 1.0f / __shfl(ls[qsub], hi4 + r);
#pragma unroll
      for (int r = 0; r < 4; r++) {
        unsigned short* op =
            O + (size_t)(b * 2048 + q0 + w * 32 + qsub * 16 + hi4 + r) * 4096 + h * 128 + fr;
#pragma unroll
        for (int nf = 0; nf < 8; nf++) op[nf * 16] = f2bf(oacc[qsub][nf][r] * iv[r]);
      }
    }
  }
}

// ---------------------------------------------------------------------------
extern "C" void kernel_launch(void* const* d_in, const int* in_sizes, int n_in,
                              void* d_out, int out_size, void* d_ws, size_t ws_size,
                              hipStream_t stream) {
  const float* hs = (const float*)d_in[0];
  const float* wq = (const float*)d_in[1];
  const float* wk = (const float*)d_in[2];
  const float* wv = (const float*)d_in[3];
  const float* wo = (const float*)d_in[4];
  const float* cosb = (const float*)d_in[5];
  const float* sinb = (const float*)d_in[6];
  // d_in[7] attn_mask: pure causal, applied structurally

  unsigned short* ws = (unsigned short*)d_ws;
  unsigned short* T1 = ws;             // 4096x4096 (WqT, later WoT)
  unsigned short* T2 = T1 + 16777216;  // 1024x4096 (WkT)
  unsigned short* T3 = T2 + 4194304;   // 1024x4096 (WvT) — contiguous after T2
  unsigned short* Qb = T3 + 4194304;   // 4096x4096
  unsigned short* KVb = Qb + 16777216; // 4096x2048 (K cols 0..1023, V 1024..2047)
  unsigned short* Ob = KVb + 8388608;  // 4096x4096

  // hs downcast lives in d_out (fp32 out buffer, consumed before O-gemm)
  unsigned short* hsb = (unsigned short*)d_out;

  dim3 tb(32, 8);
  downcast_f2b<<<8192, 256, 0, stream>>>(hs, hsb, 2097152);
  transpose_f2b<<<dim3(128, 128), tb, 0, stream>>>(wq, T1, 4096, 4096);
  transpose_f2b<<<dim3(32, 128), tb, 0, stream>>>(wk, T2, 4096, 1024);
  transpose_f2b<<<dim3(32, 128), tb, 0, stream>>>(wv, T3, 4096, 1024);

  gemm_bt<0><<<dim3(32, 32), 256, 0, stream>>>(hsb, T1, Qb, 4096, 4096, 4096);
  gemm_bt<0><<<dim3(32, 16), 256, 0, stream>>>(hsb, T2, KVb, 4096, 2048, 4096);

  transpose_f2b<<<dim3(128, 128), tb, 0, stream>>>(wo, T1, 4096, 4096);

  rope_kernel<<<4096, 256, 0, stream>>>(Qb, cosb, sinb, 5, 4096, 4096 * 32 * 8);
  rope_kernel<<<1024, 256, 0, stream>>>(KVb, cosb, sinb, 3, 2048, 4096 * 8 * 8);

  flash_attn<<<dim3(8, 32, 2), 256, 0, stream>>>(Qb, KVb, Ob);

  gemm_bt<1><<<dim3(32, 32), 256, 0, stream>>>(Ob, T1, (float*)d_out, 4096, 4096, 4096);
}